// Round 16
// baseline (218.089 us; speedup 1.0000x reference)
//
#include <hip/hip_runtime.h>
#include <math.h>

#define NB 1024
#define NM 50
#define NH 128
#define NI 100000

// flat output offsets (return order)
constexpr size_t OFF_H   = (size_t)NB * NI;              // h_new[None]  (1,B,H)
constexpr size_t OFF_EMB = OFF_H   + (size_t)NB * NH;    // embedded_input (B,1,E)
constexpr size_t OFF_GRU = OFF_EMB + (size_t)NB * NH;    // gru_output (B,1,H)
constexpr size_t OFF_ATT = OFF_GRU + (size_t)NB * NH;    // attn_weights (B,M)

typedef __attribute__((ext_vector_type(8))) short bf16x8;
typedef __attribute__((ext_vector_type(4))) float f32x4;

static __device__ __forceinline__ unsigned short f2bf(float x) {
    unsigned int u = __float_as_uint(x);
    return (unsigned short)((u + 0x7FFFu + ((u >> 16) & 1u)) >> 16);   // RNE
}
static __device__ __forceinline__ float bf2f(unsigned short v) {
    return __uint_as_float((unsigned int)v << 16);
}
static __device__ __forceinline__ float fast_tanh(float x) {
    float cx = fminf(fmaxf(x, -15.0f), 15.0f);
    float e = __expf(2.0f * cx);
    return (e - 1.0f) / (e + 1.0f);
}
static __device__ __forceinline__ float fast_sigmoid(float x) {
    float cx = fminf(fmaxf(x, -30.0f), 30.0f);
    return 1.0f / (1.0f + __expf(-cx));
}
static __device__ __forceinline__ bf16x8 pack8(float4 f0, float4 f1) {
    bf16x8 p;
    p[0] = (short)f2bf(f0.x); p[1] = (short)f2bf(f0.y);
    p[2] = (short)f2bf(f0.z); p[3] = (short)f2bf(f0.w);
    p[4] = (short)f2bf(f1.x); p[5] = (short)f2bf(f1.y);
    p[6] = (short)f2bf(f1.z); p[7] = (short)f2bf(f1.w);
    return p;
}

// ---------------- Kernel 0: lin_W f32 -> bf16 pre-convert ----------------
__global__ __launch_bounds__(256) void convW_kernel(
    const float* __restrict__ W, unsigned short* __restrict__ Wbf)
{
    const int n8 = NI * NH / 8;
    for (int i = blockIdx.x * 256 + threadIdx.x; i < n8; i += gridDim.x * 256) {
        const float* s = W + (size_t)i * 8;
        bf16x8 p = pack8(*(const float4*)s, *(const float4*)(s + 4));
        __builtin_nontemporal_store(p, reinterpret_cast<bf16x8*>(Wbf + (size_t)i * 8));
    }
}

// ---------------- Kernel 1: attention via MFMA (1 block = 1 batch) ------
__global__ __launch_bounds__(256) void attn_mfma(
    const float* __restrict__ hidden,     // (1,B,H)
    const float* __restrict__ inter,      // (B,M,H)
    const int*   __restrict__ user_list,  // (B,)
    const float* __restrict__ cat_W,      // (U,H,2H)
    const float* __restrict__ cat_b,      // (U,H)
    const float* __restrict__ scale_W,    // (U,1,H)
    float* __restrict__ attn_out,         // (B,M)
    float* __restrict__ context)          // (B,H) scratch
{
    const int b    = blockIdx.x;
    const int tid  = threadIdx.x;
    const int lane = tid & 63;
    const int wave = tid >> 6;

    __shared__ __align__(16) unsigned short A[64 * 256];  // swizzled [m][k], 32KB
    __shared__ float e_sm[64];
    __shared__ float attn_sm[64];

    const int u = user_list[b];

    for (int c = tid; c < 2048; c += 256) {
        int r = c >> 5, s = c & 31;
        float4 f0, f1;
        if (s < 16) {
            const float* src = hidden + (size_t)b * NH + s * 8;
            f0 = *(const float4*)src; f1 = *(const float4*)(src + 4);
        } else if (r < NM) {
            const float* src = inter + ((size_t)b * NM + r) * NH + (s - 16) * 8;
            f0 = *(const float4*)src; f1 = *(const float4*)(src + 4);
        } else {
            f0 = (float4){0,0,0,0}; f1 = f0;
        }
        int byte = (r * 512 + s * 16) ^ ((r & 7) << 4);
        *reinterpret_cast<bf16x8*>((char*)A + byte) = pack8(f0, f1);
    }
    if (tid < 64) e_sm[tid] = 0.0f;
    __syncthreads();

    const int lrow = lane & 15;
    const int lk8  = (lane >> 4) * 8;

    float bc[2], ws[2];
    #pragma unroll
    for (int nf = 0; nf < 2; ++nf) {
        int h = wave * 32 + nf * 16 + lrow;
        bc[nf] = cat_b[(size_t)u * NH + h];
        ws[nf] = scale_W[(size_t)u * NH + h];
    }

    f32x4 acc[4][2];
    #pragma unroll
    for (int mf = 0; mf < 4; ++mf)
        #pragma unroll
        for (int nf = 0; nf < 2; ++nf)
            acc[mf][nf] = (f32x4){0,0,0,0};

    #pragma unroll
    for (int ks = 0; ks < 8; ++ks) {           // K = 256 = 8 x 32
        bf16x8 bfr[2];
        #pragma unroll
        for (int nf = 0; nf < 2; ++nf) {
            int h = wave * 32 + nf * 16 + lrow;
            const float* wp = cat_W + ((size_t)u * NH + h) * 256 + ks * 32 + lk8;
            bfr[nf] = pack8(*(const float4*)wp, *(const float4*)(wp + 4));
        }
        #pragma unroll
        for (int mf = 0; mf < 4; ++mf) {
            int row  = mf * 16 + lrow;
            int byte = (row * 512 + ks * 64 + lk8 * 2) ^ ((row & 7) << 4);
            bf16x8 a = *reinterpret_cast<const bf16x8*>((char*)A + byte);
            acc[mf][0] = __builtin_amdgcn_mfma_f32_16x16x32_bf16(a, bfr[0], acc[mf][0], 0, 0, 0);
            acc[mf][1] = __builtin_amdgcn_mfma_f32_16x16x32_bf16(a, bfr[1], acc[mf][1], 0, 0, 0);
        }
    }

    #pragma unroll
    for (int mf = 0; mf < 4; ++mf) {
        #pragma unroll
        for (int j = 0; j < 4; ++j) {
            float s = fast_tanh(acc[mf][0][j] + bc[0]) * ws[0]
                    + fast_tanh(acc[mf][1][j] + bc[1]) * ws[1];
            s += __shfl_xor(s, 1); s += __shfl_xor(s, 2);
            s += __shfl_xor(s, 4); s += __shfl_xor(s, 8);
            if (lrow == 0) atomicAdd(&e_sm[mf * 16 + (lane >> 4) * 4 + j], s);
        }
    }
    __syncthreads();

    if (tid < 64) {
        float x = (tid < NM) ? e_sm[tid] : -INFINITY;
        float mx = x;
        #pragma unroll
        for (int s = 1; s < 64; s <<= 1) mx = fmaxf(mx, __shfl_xor(mx, s));
        float ex = (tid < NM) ? __expf(x - mx) : 0.0f;
        float sum = ex;
        #pragma unroll
        for (int s = 1; s < 64; s <<= 1) sum += __shfl_xor(sum, s);
        float aw = ex / sum;
        attn_sm[tid] = aw;
        if (tid < NM) attn_out[(size_t)b * NM + tid] = aw;
    }
    __syncthreads();

    if (tid < NH) {
        float c = 0.0f;
        #pragma unroll
        for (int m = 0; m < NM; ++m) {
            int byte = (m * 512 + (NH + tid) * 2) ^ ((m & 7) << 4);
            c = fmaf(attn_sm[m], bf2f(*reinterpret_cast<const unsigned short*>((char*)A + byte)), c);
        }
        context[(size_t)b * NH + tid] = c;
    }
}

// ---- Kernel B: GRU via MFMA, 256 blocks x 128 threads (R15) --------------
__global__ __launch_bounds__(128) void gru_mfma(
    const float* __restrict__ emb,        // (B,1,E)
    const float* __restrict__ hidden,     // (1,B,H)
    const float* __restrict__ context,    // (B,H)
    const float* __restrict__ w_ih,       // (3H,2E)
    const float* __restrict__ w_hh,       // (3H,H)
    const float* __restrict__ b_ih,       // (3H,)
    const float* __restrict__ b_hh,       // (3H,)
    float* __restrict__ out_h,            // (B,H)
    float* __restrict__ out_emb,          // (B,E)
    float* __restrict__ out_gru)          // (B,H)
{
    const int bg   = blockIdx.x >> 2;
    const int hc   = blockIdx.x & 3;
    const int b0   = bg * 16;
    const int h0   = hc * 32;
    const int tid  = threadIdx.x;
    const int lane = tid & 63;
    const int wave = tid >> 6;

    __shared__ __align__(16) unsigned short Xs[16 * 256];
    __shared__ __align__(16) unsigned short Hs[16 * 128];
    __shared__ float Gi[96][17];
    __shared__ float Gh[96][17];

    for (int c = tid; c < 768; c += 128) {
        if (c < 512) {
            int r = c >> 5, s = c & 31;
            const float* src = (s < 16)
                ? emb     + (size_t)(b0 + r) * NH + s * 8
                : context + (size_t)(b0 + r) * NH + (s - 16) * 8;
            int byte = (r * 512 + s * 16) ^ ((r & 7) << 4);
            *reinterpret_cast<bf16x8*>((char*)Xs + byte) =
                pack8(*(const float4*)src, *(const float4*)(src + 4));
        } else {
            int cc = c - 512;
            int r = cc >> 4, s = cc & 15;
            const float* src = hidden + (size_t)(b0 + r) * NH + s * 8;
            int byte = (r * 256 + s * 16) ^ ((r & 7) << 4);
            *reinterpret_cast<bf16x8*>((char*)Hs + byte) =
                pack8(*(const float4*)src, *(const float4*)(src + 4));
        }
    }
    __syncthreads();

    const int lrow = lane & 15;
    const int g16  = lane >> 4;
    const int lk8  = g16 * 8;

    bf16x8 xa[8], ha[4];
    #pragma unroll
    for (int ks = 0; ks < 8; ++ks) {
        int byte = (lrow * 512 + ks * 64 + lk8 * 2) ^ ((lrow & 7) << 4);
        xa[ks] = *reinterpret_cast<const bf16x8*>((char*)Xs + byte);
    }
    #pragma unroll
    for (int ks = 0; ks < 4; ++ks) {
        int byte = (lrow * 256 + ks * 64 + lk8 * 2) ^ ((lrow & 7) << 4);
        ha[ks] = *reinterpret_cast<const bf16x8*>((char*)Hs + byte);
    }

    #pragma unroll
    for (int f = 0; f < 3; ++f) {
        const int lb = (wave * 3 + f) * 16;
        const int l  = lb + lrow;
        const int gt = l >> 5;
        const int n  = gt * NH + h0 + (l & 31);
        f32x4 ai = (f32x4){0,0,0,0};
        f32x4 ah = (f32x4){0,0,0,0};
        const float* wi = w_ih + (size_t)n * 256;
        #pragma unroll
        for (int ks = 0; ks < 8; ++ks) {
            const float* wp = wi + ks * 32 + lk8;
            bf16x8 bv = pack8(*(const float4*)wp, *(const float4*)(wp + 4));
            ai = __builtin_amdgcn_mfma_f32_16x16x32_bf16(bv, xa[ks], ai, 0, 0, 0);
        }
        const float* wh = w_hh + (size_t)n * NH;
        #pragma unroll
        for (int ks = 0; ks < 4; ++ks) {
            const float* wp = wh + ks * 32 + lk8;
            bf16x8 bv = pack8(*(const float4*)wp, *(const float4*)(wp + 4));
            ah = __builtin_amdgcn_mfma_f32_16x16x32_bf16(bv, ha[ks], ah, 0, 0, 0);
        }
        #pragma unroll
        for (int j = 0; j < 4; ++j) {
            int lr = lb + g16 * 4 + j;
            Gi[lr][lrow] = ai[j];
            Gh[lr][lrow] = ah[j];
        }
    }
    __syncthreads();

    #pragma unroll
    for (int k = 0; k < 4; ++k) {
        int idx = k * 128 + tid;
        int bb  = idx >> 5;
        int hh  = idx & 31;
        int h   = h0 + hh;
        float gr = Gi[hh][bb]      + b_ih[h];
        float gz = Gi[32 + hh][bb] + b_ih[NH + h];
        float gn = Gi[64 + hh][bb] + b_ih[2 * NH + h];
        float hr = Gh[hh][bb]      + b_hh[h];
        float hz = Gh[32 + hh][bb] + b_hh[NH + h];
        float hn = Gh[64 + hh][bb] + b_hh[2 * NH + h];
        float r = fast_sigmoid(gr + hr);
        float z = fast_sigmoid(gz + hz);
        float n = fast_tanh(gn + r * hn);
        size_t o = (size_t)(b0 + bb) * NH + h;
        float h0v = hidden[o];
        float hnew = (1.0f - z) * n + z * h0v;
        out_h[o]   = hnew;
        out_gru[o] = hnew;
        out_emb[o] = emb[o];
    }
}

// ---- Kernel C: output projection, bf16 MFMA (low-VGPR, R11) --------------
template<bool PRE>
__global__ __launch_bounds__(256, 4) void out_mfma(
    const float* __restrict__ hnew,           // (B,H)
    const float* __restrict__ lin_W,          // (NI,H) f32
    const unsigned short* __restrict__ Wbf,   // (NI,H) bf16 (PRE only)
    const float* __restrict__ lin_b,          // (NI,)
    float* __restrict__ out)                  // (B,NI)
{
    const int L  = blockIdx.x;                 // 0..6255 ; 6256 = 8 XCDs * 782
    const int wg = (L & 7) * 782 + (L >> 3);   // bijective chunk-per-XCD remap
    const int mb = wg & 15;
    const int nb = wg >> 4;

    const int tid  = threadIdx.x;
    const int lane = tid & 63;
    const int wave = tid >> 6;

    const int b0 = mb * 64;
    const int n0 = nb * 256 + wave * 64;

    __shared__ __align__(16) unsigned char smem[32 * 260 * 4];
    unsigned short* As = (unsigned short*)smem;
    float (*Cs)[260]   = (float(*)[260])smem;

    for (int c = tid; c < 1024; c += 256) {
        int r = c >> 4;
        int s = c & 15;
        const float* src = hnew + (size_t)(b0 + r) * NH + s * 8;
        bf16x8 p = pack8(*(const float4*)src, *(const float4*)(src + 4));
        int byte = (r * 256 + s * 16) ^ ((r & 7) << 4);
        *reinterpret_cast<bf16x8*>((char*)As + byte) = p;
    }
    __syncthreads();

    const int lrow = lane & 15;
    const int g    = lane >> 4;
    const int lk8  = g * 8;

    f32x4 acc[4][4];
    #pragma unroll
    for (int mf = 0; mf < 4; ++mf)
        #pragma unroll
        for (int nf = 0; nf < 4; ++nf)
            acc[mf][nf] = (f32x4){0,0,0,0};

    #pragma unroll
    for (int ks = 0; ks < 4; ++ks) {
        bf16x8 av[4];
        #pragma unroll
        for (int mf = 0; mf < 4; ++mf) {
            int row  = mf * 16 + lrow;
            int byte = (row * 256 + ks * 64 + lk8 * 2) ^ ((row & 7) << 4);
            av[mf] = *reinterpret_cast<const bf16x8*>((char*)As + byte);
        }
        bf16x8 bv[4];
        #pragma unroll
        for (int nf = 0; nf < 4; ++nf) {
            int n = n0 + nf * 16 + lrow;
            const size_t nrow = (size_t)(n < NI ? n : 0) * NH;
            if (PRE) {
                bv[nf] = *reinterpret_cast<const bf16x8*>(Wbf + nrow + ks * 32 + lk8);
            } else {
                const float* wr = lin_W + nrow + ks * 32 + lk8;
                bv[nf] = pack8(*(const float4*)wr, *(const float4*)(wr + 4));
            }
        }
        #pragma unroll
        for (int nf = 0; nf < 4; ++nf)
            #pragma unroll
            for (int mf = 0; mf < 4; ++mf)
                acc[mf][nf] = __builtin_amdgcn_mfma_f32_16x16x32_bf16(
                    bv[nf], av[mf], acc[mf][nf], 0, 0, 0);
    }

    f32x4 bias4[4];
    #pragma unroll
    for (int nf = 0; nf < 4; ++nf) {
        int nq = n0 + nf * 16 + g * 4;
        if (nq > NI - 4) nq = NI - 4;
        const float4 bv = *(const float4*)(&lin_b[nq]);
        bias4[nf] = (f32x4){bv.x, bv.y, bv.z, bv.w};
    }

    #pragma unroll
    for (int half = 0; half < 2; ++half) {
        __syncthreads();
        #pragma unroll
        for (int mf2 = 0; mf2 < 2; ++mf2) {
            int mf = half * 2 + mf2;
            int rloc = mf2 * 16 + lrow;
            #pragma unroll
            for (int nf = 0; nf < 4; ++nf) {
                int colq = wave * 64 + nf * 16 + g * 4;
                *(f32x4*)(&Cs[rloc][colq]) = acc[mf][nf] + bias4[nf];
            }
        }
        __syncthreads();
        #pragma unroll
        for (int p = 0; p < 8; ++p) {
            int rloc = p * 4 + wave;
            int col4 = lane * 4;
            int n    = nb * 256 + col4;
            if (n < NI) {
                f32x4 v = *(const f32x4*)(&Cs[rloc][col4]);
                __builtin_nontemporal_store(v,
                    (f32x4*)(&out[(size_t)(b0 + half * 32 + rloc) * NI + n]));
            }
        }
    }
}

extern "C" void kernel_launch(void* const* d_in, const int* in_sizes, int n_in,
                              void* d_out, int out_size, void* d_ws, size_t ws_size,
                              hipStream_t stream) {
    const float* emb      = (const float*)d_in[0];
    const float* hidden   = (const float*)d_in[1];
    const float* inter    = (const float*)d_in[2];
    // d_in[3] = delta_t_h : unused by the reference
    const int*   user     = (const int*)  d_in[4];
    const float* w_ih     = (const float*)d_in[5];
    const float* w_hh     = (const float*)d_in[6];
    const float* b_ih     = (const float*)d_in[7];
    const float* b_hh     = (const float*)d_in[8];
    const float* lin_W    = (const float*)d_in[9];
    const float* lin_b    = (const float*)d_in[10];
    const float* cat_W    = (const float*)d_in[11];
    const float* cat_b    = (const float*)d_in[12];
    const float* scale_W  = (const float*)d_in[13];
    // d_in[14] = scale_b : per-batch constant energy shift -> softmax invariant

    float* out = (float*)d_out;
    const size_t wbf_bytes = (size_t)NI * NH * 2;            // 25.6 MB
    const size_t need = wbf_bytes + 512 * 1024;
    const bool pre = (ws_size >= need);

    unsigned short* Wbf = (unsigned short*)d_ws;
    float* ctx = pre ? (float*)((char*)d_ws + wbf_bytes) : (float*)d_ws;

    // MEASUREMENT ROUND: gru_mfma launched 3x (idempotent).
    // dur = R15_total + 2*T_gru. Pre-committed read: ~205-215 -> gru tiny,
    // residual is gaps/cold-cache; ~240-280 -> gru is the 20-40us pig.
    if (pre) {
        convW_kernel<<<2048, 256, 0, stream>>>(lin_W, Wbf);
        attn_mfma<<<NB, 256, 0, stream>>>(hidden, inter, user, cat_W, cat_b, scale_W,
                                          out + OFF_ATT, ctx);
        gru_mfma<<<256, 128, 0, stream>>>(emb, hidden, ctx, w_ih, w_hh, b_ih, b_hh,
                                          out + OFF_H, out + OFF_EMB, out + OFF_GRU);
        gru_mfma<<<256, 128, 0, stream>>>(emb, hidden, ctx, w_ih, w_hh, b_ih, b_hh,
                                          out + OFF_H, out + OFF_EMB, out + OFF_GRU);
        gru_mfma<<<256, 128, 0, stream>>>(emb, hidden, ctx, w_ih, w_hh, b_ih, b_hh,
                                          out + OFF_H, out + OFF_EMB, out + OFF_GRU);
        out_mfma<true><<<6256, 256, 0, stream>>>(out + OFF_H, lin_W, Wbf, lin_b, out);
    } else {
        attn_mfma<<<NB, 256, 0, stream>>>(hidden, inter, user, cat_W, cat_b, scale_W,
                                          out + OFF_ATT, ctx);
        gru_mfma<<<256, 128, 0, stream>>>(emb, hidden, ctx, w_ih, w_hh, b_ih, b_hh,
                                          out + OFF_H, out + OFF_EMB, out + OFF_GRU);
        gru_mfma<<<256, 128, 0, stream>>>(emb, hidden, ctx, w_ih, w_hh, b_ih, b_hh,
                                          out + OFF_H, out + OFF_EMB, out + OFF_GRU);
        gru_mfma<<<256, 128, 0, stream>>>(emb, hidden, ctx, w_ih, w_hh, b_ih, b_hh,
                                          out + OFF_H, out + OFF_EMB, out + OFF_GRU);
        out_mfma<false><<<6256, 256, 0, stream>>>(out + OFF_H, lin_W, nullptr, lin_b, out);
    }
}

// Round 17
// 192.290 us; speedup vs baseline: 1.1342x; 1.1342x over previous
//
#include <hip/hip_runtime.h>
#include <math.h>

#define NB 1024
#define NM 50
#define NH 128
#define NI 100000

// flat output offsets (return order)
constexpr size_t OFF_H   = (size_t)NB * NI;              // h_new[None]  (1,B,H)
constexpr size_t OFF_EMB = OFF_H   + (size_t)NB * NH;    // embedded_input (B,1,E)
constexpr size_t OFF_GRU = OFF_EMB + (size_t)NB * NH;    // gru_output (B,1,H)
constexpr size_t OFF_ATT = OFF_GRU + (size_t)NB * NH;    // attn_weights (B,M)

#define CONV_BLOCKS 512

typedef __attribute__((ext_vector_type(8))) short bf16x8;
typedef __attribute__((ext_vector_type(4))) float f32x4;

static __device__ __forceinline__ unsigned short f2bf(float x) {
    unsigned int u = __float_as_uint(x);
    return (unsigned short)((u + 0x7FFFu + ((u >> 16) & 1u)) >> 16);   // RNE
}
static __device__ __forceinline__ float bf2f(unsigned short v) {
    return __uint_as_float((unsigned int)v << 16);
}
static __device__ __forceinline__ float fast_tanh(float x) {
    float cx = fminf(fmaxf(x, -15.0f), 15.0f);
    float e = __expf(2.0f * cx);
    return (e - 1.0f) / (e + 1.0f);
}
static __device__ __forceinline__ float fast_sigmoid(float x) {
    float cx = fminf(fmaxf(x, -30.0f), 30.0f);
    return 1.0f / (1.0f + __expf(-cx));
}
static __device__ __forceinline__ bf16x8 pack8(float4 f0, float4 f1) {
    bf16x8 p;
    p[0] = (short)f2bf(f0.x); p[1] = (short)f2bf(f0.y);
    p[2] = (short)f2bf(f0.z); p[3] = (short)f2bf(f0.w);
    p[4] = (short)f2bf(f1.x); p[5] = (short)f2bf(f1.y);
    p[6] = (short)f2bf(f1.z); p[7] = (short)f2bf(f1.w);
    return p;
}

// ---- Kernel A: block-role split: conv blocks + attn blocks ---------------
// Blocks [0, CONV_BLOCKS): stream-convert lin_W f32->bf16 (runs CONCURRENTLY
// with attn on other CUs, hiding under attn's gather-bound phase).
// Blocks [CONV_BLOCKS, CONV_BLOCKS+NB): attention for batch b.
template<bool PRE>
__global__ __launch_bounds__(256) void attn_conv_split(
    const float* __restrict__ hidden,     // (1,B,H)
    const float* __restrict__ inter,      // (B,M,H)
    const int*   __restrict__ user_list,  // (B,)
    const float* __restrict__ cat_W,      // (U,H,2H)
    const float* __restrict__ cat_b,      // (U,H)
    const float* __restrict__ scale_W,    // (U,1,H)
    const float* __restrict__ lin_W,      // (NI,H) f32
    unsigned short* __restrict__ Wbf,     // (NI,H) bf16 out (PRE only)
    float* __restrict__ attn_out,         // (B,M)
    float* __restrict__ context)          // (B,H) scratch
{
    const int tid = threadIdx.x;

    // ---- conv role ----
    if (blockIdx.x < CONV_BLOCKS) {
        if (PRE) {
            const int n8 = NI * NH / 8;
            for (int i = blockIdx.x * 256 + tid; i < n8; i += CONV_BLOCKS * 256) {
                const float* s = lin_W + (size_t)i * 8;
                bf16x8 p = pack8(*(const float4*)s, *(const float4*)(s + 4));
                __builtin_nontemporal_store(p, reinterpret_cast<bf16x8*>(Wbf + (size_t)i * 8));
            }
        }
        return;
    }

    // ---- attn role ----
    const int b    = blockIdx.x - CONV_BLOCKS;
    const int lane = tid & 63;
    const int wave = tid >> 6;

    __shared__ __align__(16) unsigned short A[64 * 256];  // swizzled [m][k], 32KB
    __shared__ float e_sm[64];
    __shared__ float attn_sm[64];

    const int u = user_list[b];

    for (int c = tid; c < 2048; c += 256) {
        int r = c >> 5, s = c & 31;
        float4 f0, f1;
        if (s < 16) {
            const float* src = hidden + (size_t)b * NH + s * 8;
            f0 = *(const float4*)src; f1 = *(const float4*)(src + 4);
        } else if (r < NM) {
            const float* src = inter + ((size_t)b * NM + r) * NH + (s - 16) * 8;
            f0 = *(const float4*)src; f1 = *(const float4*)(src + 4);
        } else {
            f0 = (float4){0,0,0,0}; f1 = f0;
        }
        int byte = (r * 512 + s * 16) ^ ((r & 7) << 4);
        *reinterpret_cast<bf16x8*>((char*)A + byte) = pack8(f0, f1);
    }
    if (tid < 64) e_sm[tid] = 0.0f;
    __syncthreads();

    const int lrow = lane & 15;
    const int lk8  = (lane >> 4) * 8;

    float bc[2], ws[2];
    #pragma unroll
    for (int nf = 0; nf < 2; ++nf) {
        int h = wave * 32 + nf * 16 + lrow;
        bc[nf] = cat_b[(size_t)u * NH + h];
        ws[nf] = scale_W[(size_t)u * NH + h];
    }

    f32x4 acc[4][2];
    #pragma unroll
    for (int mf = 0; mf < 4; ++mf)
        #pragma unroll
        for (int nf = 0; nf < 2; ++nf)
            acc[mf][nf] = (f32x4){0,0,0,0};

    #pragma unroll
    for (int ks = 0; ks < 8; ++ks) {           // K = 256 = 8 x 32
        bf16x8 bfr[2];
        #pragma unroll
        for (int nf = 0; nf < 2; ++nf) {
            int h = wave * 32 + nf * 16 + lrow;
            const float* wp = cat_W + ((size_t)u * NH + h) * 256 + ks * 32 + lk8;
            bfr[nf] = pack8(*(const float4*)wp, *(const float4*)(wp + 4));
        }
        #pragma unroll
        for (int mf = 0; mf < 4; ++mf) {
            int row  = mf * 16 + lrow;
            int byte = (row * 512 + ks * 64 + lk8 * 2) ^ ((row & 7) << 4);
            bf16x8 a = *reinterpret_cast<const bf16x8*>((char*)A + byte);
            acc[mf][0] = __builtin_amdgcn_mfma_f32_16x16x32_bf16(a, bfr[0], acc[mf][0], 0, 0, 0);
            acc[mf][1] = __builtin_amdgcn_mfma_f32_16x16x32_bf16(a, bfr[1], acc[mf][1], 0, 0, 0);
        }
    }

    #pragma unroll
    for (int mf = 0; mf < 4; ++mf) {
        #pragma unroll
        for (int j = 0; j < 4; ++j) {
            float s = fast_tanh(acc[mf][0][j] + bc[0]) * ws[0]
                    + fast_tanh(acc[mf][1][j] + bc[1]) * ws[1];
            s += __shfl_xor(s, 1); s += __shfl_xor(s, 2);
            s += __shfl_xor(s, 4); s += __shfl_xor(s, 8);
            if (lrow == 0) atomicAdd(&e_sm[mf * 16 + (lane >> 4) * 4 + j], s);
        }
    }
    __syncthreads();

    if (tid < 64) {
        float x = (tid < NM) ? e_sm[tid] : -INFINITY;
        float mx = x;
        #pragma unroll
        for (int s = 1; s < 64; s <<= 1) mx = fmaxf(mx, __shfl_xor(mx, s));
        float ex = (tid < NM) ? __expf(x - mx) : 0.0f;
        float sum = ex;
        #pragma unroll
        for (int s = 1; s < 64; s <<= 1) sum += __shfl_xor(sum, s);
        float aw = ex / sum;
        attn_sm[tid] = aw;
        if (tid < NM) attn_out[(size_t)b * NM + tid] = aw;
    }
    __syncthreads();

    if (tid < NH) {
        float c = 0.0f;
        #pragma unroll
        for (int m = 0; m < NM; ++m) {
            int byte = (m * 512 + (NH + tid) * 2) ^ ((m & 7) << 4);
            c = fmaf(attn_sm[m], bf2f(*reinterpret_cast<const unsigned short*>((char*)A + byte)), c);
        }
        context[(size_t)b * NH + tid] = c;
    }
}

// ---- Kernel B: GRU via MFMA, 256 blocks x 128 threads (R15) --------------
__global__ __launch_bounds__(128) void gru_mfma(
    const float* __restrict__ emb,        // (B,1,E)
    const float* __restrict__ hidden,     // (1,B,H)
    const float* __restrict__ context,    // (B,H)
    const float* __restrict__ w_ih,       // (3H,2E)
    const float* __restrict__ w_hh,       // (3H,H)
    const float* __restrict__ b_ih,       // (3H,)
    const float* __restrict__ b_hh,       // (3H,)
    float* __restrict__ out_h,            // (B,H)
    float* __restrict__ out_emb,          // (B,E)
    float* __restrict__ out_gru)          // (B,H)
{
    const int bg   = blockIdx.x >> 2;
    const int hc   = blockIdx.x & 3;
    const int b0   = bg * 16;
    const int h0   = hc * 32;
    const int tid  = threadIdx.x;
    const int lane = tid & 63;
    const int wave = tid >> 6;

    __shared__ __align__(16) unsigned short Xs[16 * 256];
    __shared__ __align__(16) unsigned short Hs[16 * 128];
    __shared__ float Gi[96][17];
    __shared__ float Gh[96][17];

    for (int c = tid; c < 768; c += 128) {
        if (c < 512) {
            int r = c >> 5, s = c & 31;
            const float* src = (s < 16)
                ? emb     + (size_t)(b0 + r) * NH + s * 8
                : context + (size_t)(b0 + r) * NH + (s - 16) * 8;
            int byte = (r * 512 + s * 16) ^ ((r & 7) << 4);
            *reinterpret_cast<bf16x8*>((char*)Xs + byte) =
                pack8(*(const float4*)src, *(const float4*)(src + 4));
        } else {
            int cc = c - 512;
            int r = cc >> 4, s = cc & 15;
            const float* src = hidden + (size_t)(b0 + r) * NH + s * 8;
            int byte = (r * 256 + s * 16) ^ ((r & 7) << 4);
            *reinterpret_cast<bf16x8*>((char*)Hs + byte) =
                pack8(*(const float4*)src, *(const float4*)(src + 4));
        }
    }
    __syncthreads();

    const int lrow = lane & 15;
    const int g16  = lane >> 4;
    const int lk8  = g16 * 8;

    bf16x8 xa[8], ha[4];
    #pragma unroll
    for (int ks = 0; ks < 8; ++ks) {
        int byte = (lrow * 512 + ks * 64 + lk8 * 2) ^ ((lrow & 7) << 4);
        xa[ks] = *reinterpret_cast<const bf16x8*>((char*)Xs + byte);
    }
    #pragma unroll
    for (int ks = 0; ks < 4; ++ks) {
        int byte = (lrow * 256 + ks * 64 + lk8 * 2) ^ ((lrow & 7) << 4);
        ha[ks] = *reinterpret_cast<const bf16x8*>((char*)Hs + byte);
    }

    #pragma unroll
    for (int f = 0; f < 3; ++f) {
        const int lb = (wave * 3 + f) * 16;
        const int l  = lb + lrow;
        const int gt = l >> 5;
        const int n  = gt * NH + h0 + (l & 31);
        f32x4 ai = (f32x4){0,0,0,0};
        f32x4 ah = (f32x4){0,0,0,0};
        const float* wi = w_ih + (size_t)n * 256;
        #pragma unroll
        for (int ks = 0; ks < 8; ++ks) {
            const float* wp = wi + ks * 32 + lk8;
            bf16x8 bv = pack8(*(const float4*)wp, *(const float4*)(wp + 4));
            ai = __builtin_amdgcn_mfma_f32_16x16x32_bf16(bv, xa[ks], ai, 0, 0, 0);
        }
        const float* wh = w_hh + (size_t)n * NH;
        #pragma unroll
        for (int ks = 0; ks < 4; ++ks) {
            const float* wp = wh + ks * 32 + lk8;
            bf16x8 bv = pack8(*(const float4*)wp, *(const float4*)(wp + 4));
            ah = __builtin_amdgcn_mfma_f32_16x16x32_bf16(bv, ha[ks], ah, 0, 0, 0);
        }
        #pragma unroll
        for (int j = 0; j < 4; ++j) {
            int lr = lb + g16 * 4 + j;
            Gi[lr][lrow] = ai[j];
            Gh[lr][lrow] = ah[j];
        }
    }
    __syncthreads();

    #pragma unroll
    for (int k = 0; k < 4; ++k) {
        int idx = k * 128 + tid;
        int bb  = idx >> 5;
        int hh  = idx & 31;
        int h   = h0 + hh;
        float gr = Gi[hh][bb]      + b_ih[h];
        float gz = Gi[32 + hh][bb] + b_ih[NH + h];
        float gn = Gi[64 + hh][bb] + b_ih[2 * NH + h];
        float hr = Gh[hh][bb]      + b_hh[h];
        float hz = Gh[32 + hh][bb] + b_hh[NH + h];
        float hn = Gh[64 + hh][bb] + b_hh[2 * NH + h];
        float r = fast_sigmoid(gr + hr);
        float z = fast_sigmoid(gz + hz);
        float n = fast_tanh(gn + r * hn);
        size_t o = (size_t)(b0 + bb) * NH + h;
        float h0v = hidden[o];
        float hnew = (1.0f - z) * n + z * h0v;
        out_h[o]   = hnew;
        out_gru[o] = hnew;
        out_emb[o] = emb[o];
    }
}

// ---- Kernel C: output projection, bf16 MFMA (low-VGPR, R11) --------------
template<bool PRE>
__global__ __launch_bounds__(256, 4) void out_mfma(
    const float* __restrict__ hnew,           // (B,H)
    const float* __restrict__ lin_W,          // (NI,H) f32
    const unsigned short* __restrict__ Wbf,   // (NI,H) bf16 (PRE only)
    const float* __restrict__ lin_b,          // (NI,)
    float* __restrict__ out)                  // (B,NI)
{
    const int L  = blockIdx.x;                 // 0..6255 ; 6256 = 8 XCDs * 782
    const int wg = (L & 7) * 782 + (L >> 3);   // bijective chunk-per-XCD remap
    const int mb = wg & 15;
    const int nb = wg >> 4;

    const int tid  = threadIdx.x;
    const int lane = tid & 63;
    const int wave = tid >> 6;

    const int b0 = mb * 64;
    const int n0 = nb * 256 + wave * 64;

    __shared__ __align__(16) unsigned char smem[32 * 260 * 4];
    unsigned short* As = (unsigned short*)smem;
    float (*Cs)[260]   = (float(*)[260])smem;

    for (int c = tid; c < 1024; c += 256) {
        int r = c >> 4;
        int s = c & 15;
        const float* src = hnew + (size_t)(b0 + r) * NH + s * 8;
        bf16x8 p = pack8(*(const float4*)src, *(const float4*)(src + 4));
        int byte = (r * 256 + s * 16) ^ ((r & 7) << 4);
        *reinterpret_cast<bf16x8*>((char*)As + byte) = p;
    }
    __syncthreads();

    const int lrow = lane & 15;
    const int g    = lane >> 4;
    const int lk8  = g * 8;

    f32x4 acc[4][4];
    #pragma unroll
    for (int mf = 0; mf < 4; ++mf)
        #pragma unroll
        for (int nf = 0; nf < 4; ++nf)
            acc[mf][nf] = (f32x4){0,0,0,0};

    #pragma unroll
    for (int ks = 0; ks < 4; ++ks) {
        bf16x8 av[4];
        #pragma unroll
        for (int mf = 0; mf < 4; ++mf) {
            int row  = mf * 16 + lrow;
            int byte = (row * 256 + ks * 64 + lk8 * 2) ^ ((row & 7) << 4);
            av[mf] = *reinterpret_cast<const bf16x8*>((char*)As + byte);
        }
        bf16x8 bv[4];
        #pragma unroll
        for (int nf = 0; nf < 4; ++nf) {
            int n = n0 + nf * 16 + lrow;
            const size_t nrow = (size_t)(n < NI ? n : 0) * NH;
            if (PRE) {
                bv[nf] = *reinterpret_cast<const bf16x8*>(Wbf + nrow + ks * 32 + lk8);
            } else {
                const float* wr = lin_W + nrow + ks * 32 + lk8;
                bv[nf] = pack8(*(const float4*)wr, *(const float4*)(wr + 4));
            }
        }
        #pragma unroll
        for (int nf = 0; nf < 4; ++nf)
            #pragma unroll
            for (int mf = 0; mf < 4; ++mf)
                acc[mf][nf] = __builtin_amdgcn_mfma_f32_16x16x32_bf16(
                    bv[nf], av[mf], acc[mf][nf], 0, 0, 0);
    }

    f32x4 bias4[4];
    #pragma unroll
    for (int nf = 0; nf < 4; ++nf) {
        int nq = n0 + nf * 16 + g * 4;
        if (nq > NI - 4) nq = NI - 4;
        const float4 bv = *(const float4*)(&lin_b[nq]);
        bias4[nf] = (f32x4){bv.x, bv.y, bv.z, bv.w};
    }

    #pragma unroll
    for (int half = 0; half < 2; ++half) {
        __syncthreads();
        #pragma unroll
        for (int mf2 = 0; mf2 < 2; ++mf2) {
            int mf = half * 2 + mf2;
            int rloc = mf2 * 16 + lrow;
            #pragma unroll
            for (int nf = 0; nf < 4; ++nf) {
                int colq = wave * 64 + nf * 16 + g * 4;
                *(f32x4*)(&Cs[rloc][colq]) = acc[mf][nf] + bias4[nf];
            }
        }
        __syncthreads();
        #pragma unroll
        for (int p = 0; p < 8; ++p) {
            int rloc = p * 4 + wave;
            int col4 = lane * 4;
            int n    = nb * 256 + col4;
            if (n < NI) {
                f32x4 v = *(const f32x4*)(&Cs[rloc][col4]);
                __builtin_nontemporal_store(v,
                    (f32x4*)(&out[(size_t)(b0 + half * 32 + rloc) * NI + n]));
            }
        }
    }
}

extern "C" void kernel_launch(void* const* d_in, const int* in_sizes, int n_in,
                              void* d_out, int out_size, void* d_ws, size_t ws_size,
                              hipStream_t stream) {
    const float* emb      = (const float*)d_in[0];
    const float* hidden   = (const float*)d_in[1];
    const float* inter    = (const float*)d_in[2];
    // d_in[3] = delta_t_h : unused by the reference
    const int*   user     = (const int*)  d_in[4];
    const float* w_ih     = (const float*)d_in[5];
    const float* w_hh     = (const float*)d_in[6];
    const float* b_ih     = (const float*)d_in[7];
    const float* b_hh     = (const float*)d_in[8];
    const float* lin_W    = (const float*)d_in[9];
    const float* lin_b    = (const float*)d_in[10];
    const float* cat_W    = (const float*)d_in[11];
    const float* cat_b    = (const float*)d_in[12];
    const float* scale_W  = (const float*)d_in[13];
    // d_in[14] = scale_b : per-batch constant energy shift -> softmax invariant

    float* out = (float*)d_out;
    const size_t wbf_bytes = (size_t)NI * NH * 2;            // 25.6 MB
    const size_t need = wbf_bytes + 512 * 1024;
    const bool pre = (ws_size >= need);

    unsigned short* Wbf = (unsigned short*)d_ws;
    float* ctx = pre ? (float*)((char*)d_ws + wbf_bytes) : (float*)d_ws;

    if (pre) {
        attn_conv_split<true><<<CONV_BLOCKS + NB, 256, 0, stream>>>(
            hidden, inter, user, cat_W, cat_b, scale_W, lin_W, Wbf,
            out + OFF_ATT, ctx);
        gru_mfma<<<256, 128, 0, stream>>>(emb, hidden, ctx, w_ih, w_hh, b_ih, b_hh,
                                          out + OFF_H, out + OFF_EMB, out + OFF_GRU);
        out_mfma<true><<<6256, 256, 0, stream>>>(out + OFF_H, lin_W, Wbf, lin_b, out);
    } else {
        attn_conv_split<false><<<CONV_BLOCKS + NB, 256, 0, stream>>>(
            hidden, inter, user, cat_W, cat_b, scale_W, lin_W, nullptr,
            out + OFF_ATT, ctx);
        gru_mfma<<<256, 128, 0, stream>>>(emb, hidden, ctx, w_ih, w_hh, b_ih, b_hh,
                                          out + OFF_H, out + OFF_EMB, out + OFF_GRU);
        out_mfma<false><<<6256, 256, 0, stream>>>(out + OFF_H, lin_W, nullptr, lin_b, out);
    }
}